// Round 16
// baseline (755.458 us; speedup 1.0000x reference)
//
#include <hip/hip_runtime.h>

// ---------------------------------------------------------------------------
// ChatGLM attention block on MI355X (gfx950), bf16 MFMA pipeline.
//   S=2048, B=1, H=4096, NH=32, HD=128, ROT=64.
// Stages: cvt(hs+Wqkv, merged) -> GEMM1(qkv) -> rope(+V transpose)
//         -> attention (+Wd-convert tail blocks) -> GEMM2 -> out.
// GEMM1: r11's 256x256/BK=64/4-phase, single-barrier-per-phase, vmcnt(6).
// GEMM2: 128x256, 256 blocks = exactly 1 round, direct f32+bias epilogue.
// Attention r16: grid 1024 (64 q-rows/block, wave=16 rows), launch_bounds
//   (256,4) -> 4 waves/SIMD (vs 2): attn was grid-limited at 2 blocks/CU
//   with VGPR 96 (occupancy 19%, MfmaUtil 9%). 4-way balanced qb grouping.
// ---------------------------------------------------------------------------

#define S_LEN 2048
#define NHEAD 32
#define HDIM 128
#define HID 4096

typedef float f32x4 __attribute__((ext_vector_type(4)));
typedef __bf16 bf16x8 __attribute__((ext_vector_type(8)));
typedef __bf16 bf16x4 __attribute__((ext_vector_type(4)));
typedef _Float16 f16x4 __attribute__((ext_vector_type(4)));
typedef _Float16 f16x8 __attribute__((ext_vector_type(8)));

__device__ __forceinline__ void gload16(const void* g, void* l) {
  __builtin_amdgcn_global_load_lds(
      (const __attribute__((address_space(1))) void*)g,
      (__attribute__((address_space(3))) void*)l, 16, 0, 0);
}

__device__ __forceinline__ void cvt4(const float* in, __bf16* out, int i) {
  f32x4 v = *(const f32x4*)(in + (size_t)i * 4);
  bf16x4 o;
  o[0] = (__bf16)v[0]; o[1] = (__bf16)v[1];
  o[2] = (__bf16)v[2]; o[3] = (__bf16)v[3];
  *(bf16x4*)(out + (size_t)i * 4) = o;
}

// ----------------- merged f32->bf16 convert (hs + Wqkv) --------------------
__global__ __launch_bounds__(256) void cvt2_kernel(
    const float* __restrict__ in1, __bf16* __restrict__ out1, int n4_1,
    const float* __restrict__ in2, __bf16* __restrict__ out2, int n4_2) {
  int i = blockIdx.x * 256 + threadIdx.x;
  if (i < n4_1) {
    cvt4(in1, out1, i);
  } else if (i - n4_1 < n4_2) {
    cvt4(in2, out2, i - n4_1);
  }
}

// ------------------- shared GEMM staging / fragment utils ------------------
template <int UNITS>
__device__ __forceinline__ void stage_rows(const __bf16* __restrict__ G,
                                           int grow0, int Kstride, int kofs,
                                           __bf16* lds, int tid) {
#pragma unroll
  for (int i = 0; i < UNITS; ++i) {
    int idx = i * 512 + tid;
    int rr = idx >> 3;
    int offp = (idx & 7) * 16;
    int off = offp ^ ((rr & 7) << 4);
    const char* src =
        (const char*)(G + (size_t)(grow0 + rr) * Kstride + kofs) + off;
    char* dst = (char*)lds + idx * 16;
    gload16(src, dst);
  }
}

__device__ __forceinline__ bf16x8 ldsfrag(const __bf16* hb, int rowin, int ks,
                                          int lg) {
  int off = ((ks * 64 + lg * 16) ^ ((rowin & 7) << 4));
  return *(const bf16x8*)((const char*)hb + rowin * 128 + off);
}

#define READ_A(DST, SLOT)                                                     \
  _Pragma("unroll") for (int mi = 0; mi < 4; ++mi)                            \
      _Pragma("unroll") for (int ks = 0; ks < 2; ++ks) DST[mi][ks] =          \
      ldsfrag(SLOT, wm * 64 + mi * 16 + lr, ks, lg);

#define READ_B(DST, SLOT)                                                     \
  _Pragma("unroll") for (int nj = 0; nj < 2; ++nj)                            \
      _Pragma("unroll") for (int ks = 0; ks < 2; ++ks) DST[nj][ks] =          \
      ldsfrag(SLOT, wn * 32 + nj * 16 + lr, ks, lg);

#define MFMA_Q(MH, NH, AFR, BFR)                                              \
  __builtin_amdgcn_s_setprio(1);                                              \
  _Pragma("unroll") for (int mi = 0; mi < 4; ++mi)                            \
      _Pragma("unroll") for (int nj = 0; nj < 2; ++nj)                        \
          _Pragma("unroll") for (int ks = 0; ks < 2; ++ks)                    \
              acc[MH][NH][mi][nj] =                                           \
      __builtin_amdgcn_mfma_f32_16x16x32_bf16(AFR[mi][ks], BFR[nj][ks],       \
                                              acc[MH][NH][mi][nj], 0, 0, 0);  \
  __builtin_amdgcn_s_setprio(0);

#define BAR asm volatile("s_barrier" ::: "memory");

// ---------------- GEMM1: 256x256, C = A*B^T + bias (bf16) ------------------
__global__ __launch_bounds__(512, 2) void gemm256_kernel(
    const __bf16* __restrict__ A, const __bf16* __restrict__ B,
    const float* __restrict__ bias, __bf16* __restrict__ Cout, int M, int N,
    int K, int mtiles) {
  __shared__ __align__(16) __bf16 As[2][2][128 * 64];
  __shared__ __align__(16) __bf16 Bs[2][2][128 * 64];
  const int tid = threadIdx.x;
  int bid = blockIdx.x;
  int per_patch = mtiles * 8;
  int p = bid / per_patch, r = bid % per_patch;
  int mt = r % mtiles, nt = p * 8 + r / mtiles;
  int m0 = mt * 256, n0 = nt * 256;
  const int wid = tid >> 6, l = tid & 63;
  const int wm = wid >> 2, wn = wid & 3;  // 2 x 4 waves, wave = 64 x 32
  const int lr = l & 15, lg = l >> 4;
  const int nk = K >> 6;

  f32x4 acc[2][2][4][2];
#pragma unroll
  for (int a = 0; a < 2; ++a)
#pragma unroll
    for (int b = 0; b < 2; ++b)
#pragma unroll
      for (int c = 0; c < 4; ++c)
#pragma unroll
        for (int d = 0; d < 2; ++d) acc[a][b][c][d] = 0.f;

  stage_rows<2>(A, m0, K, 0, &As[0][0][0], tid);
  stage_rows<2>(B, n0, K, 0, &Bs[0][0][0], tid);
  stage_rows<2>(B, n0 + 128, K, 0, &Bs[0][1][0], tid);
  stage_rows<2>(A, m0 + 128, K, 0, &As[0][1][0], tid);
  if (nk > 1) {
    stage_rows<2>(A, m0, K, 64, &As[1][0][0], tid);
    stage_rows<2>(B, n0, K, 64, &Bs[1][0][0], tid);
    stage_rows<2>(B, n0 + 128, K, 64, &Bs[1][1][0], tid);
    asm volatile("s_waitcnt vmcnt(6)" ::: "memory");
  } else {
    asm volatile("s_waitcnt vmcnt(0)" ::: "memory");
  }
  BAR;

  for (int t = 0; t < nk; ++t) {
    const int cur = t & 1, nxt = cur ^ 1;
    const int kt1 = (t + 1) * 64;
    const int kt2 = (t + 2) * 64;
    const bool s1 = (t + 1 < nk), s2 = (t + 2 < nk);
    bf16x8 a[4][2], b0[2][2], b1[2][2];

    // ---- p1 ----
    READ_A(a, &As[cur][0][0]);
    READ_B(b0, &Bs[cur][0][0]);
    if (s1) stage_rows<2>(A, m0 + 128, K, kt1, &As[nxt][1][0], tid);
    BAR;
    MFMA_Q(0, 0, a, b0);

    // ---- p2 ----
    READ_B(b1, &Bs[cur][1][0]);
    if (s2) stage_rows<2>(A, m0, K, kt2, &As[cur][0][0], tid);
    BAR;
    MFMA_Q(0, 1, a, b1);

    // ---- p3 ----
    READ_A(a, &As[cur][1][0]);
    if (s2) stage_rows<2>(B, n0 + 128, K, kt2, &Bs[cur][1][0], tid);
    BAR;
    MFMA_Q(1, 1, a, b1);

    // ---- p4 ----
    if (s2) stage_rows<2>(B, n0, K, kt2, &Bs[cur][0][0], tid);
    BAR;
    MFMA_Q(1, 0, a, b0);
    if (s2)
      asm volatile("s_waitcnt vmcnt(6)" ::: "memory");
    else
      asm volatile("s_waitcnt vmcnt(0)" ::: "memory");
  }

#pragma unroll
  for (int mh = 0; mh < 2; ++mh)
#pragma unroll
    for (int nh = 0; nh < 2; ++nh)
#pragma unroll
      for (int mi = 0; mi < 4; ++mi)
#pragma unroll
        for (int nj = 0; nj < 2; ++nj) {
          int row = m0 + mh * 128 + wm * 64 + mi * 16 + lg * 4;
          int col = n0 + nh * 128 + wn * 32 + nj * 16 + lr;
          float bv = bias[col];
          f32x4 v = acc[mh][nh][mi][nj];
#pragma unroll
          for (int j = 0; j < 4; ++j)
            Cout[(size_t)(row + j) * N + col] = (__bf16)(v[j] + bv);
        }
}

// ------------------- GEMM2: 128x256, C = A*B^T + bias (f32) ----------------
__global__ __launch_bounds__(512, 2) void gemm128_kernel(
    const __bf16* __restrict__ A, const __bf16* __restrict__ B,
    const float* __restrict__ bias, float* __restrict__ Cout, int M, int N,
    int K, int mtiles) {
  __shared__ __align__(16) __bf16 As[2][128 * 64];
  __shared__ __align__(16) __bf16 Bs[2][2][128 * 64];
  const int tid = threadIdx.x;
  int bid = blockIdx.x;
  int per_patch = mtiles * 8;
  int p = bid / per_patch, r = bid % per_patch;
  int mt = r % mtiles, nt = p * 8 + r / mtiles;
  int m0 = mt * 128, n0 = nt * 256;
  const int wid = tid >> 6, l = tid & 63;
  const int wm = wid >> 2, wn = wid & 3;
  const int lr = l & 15, lg = l >> 4;
  const int nk = K >> 6;

  f32x4 acc[4][4];
#pragma unroll
  for (int a = 0; a < 4; ++a)
#pragma unroll
    for (int b = 0; b < 4; ++b) acc[a][b] = 0.f;

  const int bhalf = wn >> 1;
  const int br0 = (wn & 1) * 64;

  stage_rows<2>(A, m0, K, 0, &As[0][0], tid);
  stage_rows<2>(B, n0, K, 0, &Bs[0][0][0], tid);
  stage_rows<2>(B, n0 + 128, K, 0, &Bs[0][1][0], tid);
  stage_rows<2>(A, m0, K, 64, &As[1][0], tid);
  stage_rows<2>(B, n0, K, 64, &Bs[1][0][0], tid);
  stage_rows<2>(B, n0 + 128, K, 64, &Bs[1][1][0], tid);
  asm volatile("s_waitcnt vmcnt(6)" ::: "memory");
  BAR;

  for (int t = 0; t < nk; ++t) {
    const int cur = t & 1;
    const int kt2 = (t + 2) * 64;
    const bool s2 = (t + 2 < nk);
    const __bf16* bslot = &Bs[cur][bhalf][0];
    bf16x8 a0[4], b0[4], a1[4], b1[4];

#pragma unroll
    for (int mi = 0; mi < 4; ++mi)
      a0[mi] = ldsfrag(&As[cur][0], wm * 64 + mi * 16 + lr, 0, lg);
#pragma unroll
    for (int nj = 0; nj < 4; ++nj)
      b0[nj] = ldsfrag(bslot, br0 + nj * 16 + lr, 0, lg);
    BAR;
    __builtin_amdgcn_s_setprio(1);
#pragma unroll
    for (int mi = 0; mi < 4; ++mi)
#pragma unroll
      for (int nj = 0; nj < 4; ++nj)
        acc[mi][nj] = __builtin_amdgcn_mfma_f32_16x16x32_bf16(
            a0[mi], b0[nj], acc[mi][nj], 0, 0, 0);
    __builtin_amdgcn_s_setprio(0);

#pragma unroll
    for (int mi = 0; mi < 4; ++mi)
      a1[mi] = ldsfrag(&As[cur][0], wm * 64 + mi * 16 + lr, 1, lg);
#pragma unroll
    for (int nj = 0; nj < 4; ++nj)
      b1[nj] = ldsfrag(bslot, br0 + nj * 16 + lr, 1, lg);
    BAR;
    if (s2) {
      stage_rows<2>(A, m0, K, kt2, &As[cur][0], tid);
      stage_rows<2>(B, n0, K, kt2, &Bs[cur][0][0], tid);
      stage_rows<2>(B, n0 + 128, K, kt2, &Bs[cur][1][0], tid);
    }
    __builtin_amdgcn_s_setprio(1);
#pragma unroll
    for (int mi = 0; mi < 4; ++mi)
#pragma unroll
      for (int nj = 0; nj < 4; ++nj)
        acc[mi][nj] = __builtin_amdgcn_mfma_f32_16x16x32_bf16(
            a1[mi], b1[nj], acc[mi][nj], 0, 0, 0);
    __builtin_amdgcn_s_setprio(0);
    if (s2)
      asm volatile("s_waitcnt vmcnt(6)" ::: "memory");
    else
      asm volatile("s_waitcnt vmcnt(0)" ::: "memory");
  }

#pragma unroll
  for (int mi = 0; mi < 4; ++mi)
#pragma unroll
    for (int nj = 0; nj < 4; ++nj) {
      int row = m0 + wm * 64 + mi * 16 + lg * 4;
      int col = n0 + wn * 64 + nj * 16 + lr;
      float bv = bias[col];
      f32x4 v = acc[mi][nj];
#pragma unroll
      for (int j = 0; j < 4; ++j)
        Cout[(size_t)(row + j) * N + col] = v[j] + bv;
    }
}

// ------------------------------- RoPE -------------------------------------
__global__ __launch_bounds__(256) void rope_kernel(
    const __bf16* __restrict__ qkv, const int* __restrict__ pos_ids,
    __bf16* __restrict__ Q, __bf16* __restrict__ K, _Float16* __restrict__ VT) {
  int h = blockIdx.x & 31, sb = blockIdx.x >> 5;
  int s0 = sb * 64;
  int t = threadIdx.x;
  __shared__ float cs[64][2][2][32];
  __shared__ _Float16 vs[64][132];

  for (int idx = t; idx < 64 * 64; idx += 256) {
    int sl = idx >> 6, half = (idx >> 5) & 1, i = idx & 31;
    int p = pos_ids[half * S_LEN + s0 + sl];
    float f = powf(10000.f, -(float)i / 32.f);
    float ang = (float)p * f;
    cs[sl][half][0][i] = cosf(ang);
    cs[sl][half][1][i] = sinf(ang);
  }
#pragma unroll
  for (int c = 0; c < 4; c++) {
    int chunk = c * 256 + t;
    int slv = chunk >> 4, co = (chunk & 15) * 8;
    const __bf16* vsrc =
        qkv + (size_t)(s0 + slv) * (NHEAD * 3 * HDIM) + h * 384 + 256 + co;
    bf16x8 vv = *(const bf16x8*)vsrc;
    f16x4 a, b;
#pragma unroll
    for (int j = 0; j < 4; j++) {
      a[j] = (_Float16)(float)vv[j];
      b[j] = (_Float16)(float)vv[4 + j];
    }
    *(f16x4*)&vs[slv][co] = a;
    *(f16x4*)&vs[slv][co + 4] = b;
  }
  __syncthreads();

  {
    int sl = t >> 2, role = t & 3;
    int isK = role >> 1, half = role & 1;
    const __bf16* src = qkv + (size_t)(s0 + sl) * (NHEAD * 3 * HDIM) + h * 384 +
                        isK * 128 + half * 64;
    float scale = isK ? 1.f : 0.08838834764831845f;  // 1/sqrt(128)
    float x[64];
    bf16x8 buf[8];
#pragma unroll
    for (int c = 0; c < 8; c++) buf[c] = *(const bf16x8*)(src + c * 8);
#pragma unroll
    for (int c = 0; c < 8; c++)
#pragma unroll
      for (int j = 0; j < 8; j++) x[c * 8 + j] = (float)buf[c][j];
    bf16x8 ob[8];
#pragma unroll
    for (int i = 0; i < 64; i++) {
      int ii = i & 31;
      float cv = cs[sl][half][0][ii], sv = cs[sl][half][1][ii];
      float partner = (i < 32) ? x[i + 32] : x[i - 32];
      float sgn = (i < 32) ? -1.f : 1.f;
      float o = (x[i] * cv + sgn * partner * sv) * scale;
      ob[i >> 3][i & 7] = (__bf16)o;
    }
    __bf16* dst = (isK ? K : Q) + ((size_t)h * S_LEN + s0 + sl) * HDIM + half * 64;
#pragma unroll
    for (int c = 0; c < 8; c++) *(bf16x8*)(dst + c * 8) = ob[c];
  }

#pragma unroll
  for (int c = 0; c < 4; c++) {
    int chunk = c * 256 + t;
    int d = chunk >> 3, so = (chunk & 7) * 8;
    f16x8 o;
#pragma unroll
    for (int j = 0; j < 8; j++) o[j] = vs[so + j][d];
    *(f16x8*)(VT + ((size_t)h * HDIM + d) * S_LEN + s0 + so) = o;
  }
}

// ---------------------------- Flash attention ------------------------------
// Blocks [0,1024): attention. h = b&31, x = b>>5 in 0..31; 4-way balanced
// grouping: CU slot-groups {x, x+8, x+16, x+24} get qb summing to 62.
// 4 waves/block, wave owns 16 q rows; KVBLK=32. launch_bounds(256,4) ->
// 4 blocks/CU = 16 waves/CU (attn was grid-limited at 2 blocks/CU).
// Blocks [1024,1152): f32->bf16 convert of Wd.
__global__ __launch_bounds__(256, 4) void attn_kernel(
    const __bf16* __restrict__ Q, const __bf16* __restrict__ K,
    const _Float16* __restrict__ VT, __bf16* __restrict__ ctx,
    const float* __restrict__ Wd, __bf16* __restrict__ wdb) {
  int b = blockIdx.x;
  if (b >= 1024) {
    const int n4 = HID * HID / 4;
    for (int i = (b - 1024) * 256 + threadIdx.x; i < n4; i += 128 * 256)
      cvt4(Wd, wdb, i);
    return;
  }
  int h = b & 31;
  int x = b >> 5;
  int xi = x & 7, g = x >> 3;
  int qb = (g == 0) ? 31 - xi : (g == 1) ? xi : (g == 2) ? 23 - xi : 8 + xi;
  int w = threadIdx.x >> 6, l = threadIdx.x & 63;
  int lr = l & 15, lg = l >> 4;
  int q0 = qb * 64 + w * 16;
  const __bf16* Qh = Q + (size_t)h * S_LEN * HDIM;
  const __bf16* Kh = K + (size_t)h * S_LEN * HDIM;
  const _Float16* Vh = VT + (size_t)h * HDIM * S_LEN;

  bf16x8 qf[4];
#pragma unroll
  for (int kk = 0; kk < 4; kk++)
    qf[kk] = *(const bf16x8*)(Qh + (size_t)(q0 + lr) * HDIM + kk * 32 + lg * 8);

  f32x4 acc[8];
#pragma unroll
  for (int tt = 0; tt < 8; tt++) acc[tt] = 0.f;
  float m = -INFINITY, ls = 0.f;
  int qg = q0 + lr;
  int qmax = q0 + 15;

  for (int kv0 = 0; kv0 <= qmax; kv0 += 32) {
    // ---- QK^T, both kv-subtiles ----
    f32x4 st0 = 0.f, st1 = 0.f;
#pragma unroll
    for (int kk = 0; kk < 4; kk++) {
      bf16x8 kf0 =
          *(const bf16x8*)(Kh + (size_t)(kv0 + lr) * HDIM + kk * 32 + lg * 8);
      bf16x8 kf1 = *(const bf16x8*)(Kh + (size_t)(kv0 + 16 + lr) * HDIM +
                                    kk * 32 + lg * 8);
      st0 = __builtin_amdgcn_mfma_f32_16x16x32_bf16(kf0, qf[kk], st0, 0, 0, 0);
      st1 = __builtin_amdgcn_mfma_f32_16x16x32_bf16(kf1, qf[kk], st1, 0, 0, 0);
    }

    // ---- causal mask + per-row max ----
    float tm = -INFINITY;
#pragma unroll
    for (int j = 0; j < 4; j++) {
      int kvg0 = kv0 + lg * 4 + j;
      int kvg1 = kvg0 + 16;
      if (kvg0 > qg) st0[j] = -INFINITY;
      if (kvg1 > qg) st1[j] = -INFINITY;
      tm = fmaxf(tm, fmaxf(st0[j], st1[j]));
    }
    tm = fmaxf(tm, __shfl_xor(tm, 16));
    tm = fmaxf(tm, __shfl_xor(tm, 32));
    int need = __any(tm > m);
    float mn = fmaxf(m, tm);

    f16x4 pa0, pa1;
    float ts = 0.f;
#pragma unroll
    for (int j = 0; j < 4; j++) {
      float p0 = __expf(st0[j] - mn);
      float p1 = __expf(st1[j] - mn);
      ts += p0 + p1;
      pa0[j] = (_Float16)p0;
      pa1[j] = (_Float16)p1;
    }
    ts += __shfl_xor(ts, 16);
    ts += __shfl_xor(ts, 32);

    if (need) {
      float sc = __expf(m - mn);
      ls = ls * sc + ts;
      float sj[4];
#pragma unroll
      for (int j = 0; j < 4; j++) sj[j] = __shfl(sc, lg * 4 + j);
#pragma unroll
      for (int tt = 0; tt < 8; tt++)
#pragma unroll
        for (int j = 0; j < 4; j++) acc[tt][j] *= sj[j];
    } else {
      ls += ts;
    }
    m = mn;

    // ---- PV, both subtiles (loads inside; 4 waves/SIMD hide latency) ----
#pragma unroll
    for (int tt = 0; tt < 8; tt++) {
      const _Float16* vcol = Vh + (size_t)(tt * 16 + lr) * S_LEN;
      f16x4 vb0 = *(const f16x4*)(vcol + kv0 + lg * 4);
      f16x4 vb1 = *(const f16x4*)(vcol + kv0 + 16 + lg * 4);
      acc[tt] = __builtin_amdgcn_mfma_f32_16x16x16f16(pa0, vb0, acc[tt], 0, 0, 0);
      acc[tt] = __builtin_amdgcn_mfma_f32_16x16x16f16(pa1, vb1, acc[tt], 0, 0, 0);
    }
  }

  float rj[4];
#pragma unroll
  for (int j = 0; j < 4; j++) rj[j] = 1.f / __shfl(ls, lg * 4 + j);
#pragma unroll
  for (int tt = 0; tt < 8; tt++) {
#pragma unroll
    for (int j = 0; j < 4; j++) {
      int qo = q0 + lg * 4 + j;
      ctx[(size_t)qo * (NHEAD * HDIM) + h * HDIM + tt * 16 + lr] =
          (__bf16)(acc[tt][j] * rj[j]);
    }
  }
}

// ---------------------------------------------------------------------------
extern "C" void kernel_launch(void* const* d_in, const int* in_sizes, int n_in,
                              void* d_out, int out_size, void* d_ws,
                              size_t ws_size, hipStream_t stream) {
  const float* hs = (const float*)d_in[0];
  const int* pos_ids = (const int*)d_in[1];
  const float* Wqkv = (const float*)d_in[4];
  const float* bqkv = (const float*)d_in[5];
  const float* Wd = (const float*)d_in[6];
  const float* bd = (const float*)d_in[7];
  float* out = (float*)d_out;

  char* ws = (char*)d_ws;
  constexpr size_t OFF_W = 16777216ULL;
  constexpr size_t OFF_QKV = OFF_W + 100663296ULL;
  constexpr size_t OFF_Q = OFF_QKV + 50331648ULL;
  constexpr size_t OFF_K = OFF_Q + 16777216ULL;
  constexpr size_t OFF_V = OFF_K + 16777216ULL;
  __bf16* hsb = (__bf16*)(ws);
  __bf16* wqkvb = (__bf16*)(ws + OFF_W);
  __bf16* wdb = (__bf16*)(ws + OFF_W);  // aliases wqkvb (dead after GEMM1)
  __bf16* qkvb = (__bf16*)(ws + OFF_QKV);
  __bf16* ctxb = qkvb;                  // aliases qkv (dead after rope)
  __bf16* Qb = (__bf16*)(ws + OFF_Q);
  __bf16* Kb = (__bf16*)(ws + OFF_K);
  _Float16* Vtb = (_Float16*)(ws + OFF_V);

  const int n4_hs = S_LEN * HID / 4;
  const int n4_w = 3 * HID * HID / 4;
  cvt2_kernel<<<(n4_hs + n4_w + 255) / 256, 256, 0, stream>>>(
      hs, hsb, n4_hs, Wqkv, wqkvb, n4_w);

  // GEMM1: [2048,4096] x [12288,4096]^T -> bf16 qkv. 8x48 tiles of 256^2.
  gemm256_kernel<<<8 * 48, 512, 0, stream>>>(hsb, wqkvb, bqkv, qkvb, S_LEN,
                                             3 * HID, HID, 8);

  rope_kernel<<<NHEAD * (S_LEN / 64), 256, 0, stream>>>(qkvb, pos_ids, Qb, Kb,
                                                        Vtb);

  // attention (1024 blocks, 64 q-rows each) + Wd convert (128 tail blocks).
  attn_kernel<<<1024 + 128, 256, 0, stream>>>(Qb, Kb, Vtb, ctxb, Wd, wdb);

  // GEMM2: [2048,4096] x [4096,4096]^T + bd -> f32 out. 16x16 = 256 tiles
  // of 128x256 = exactly 1 round.
  gemm128_kernel<<<16 * 16, 512, 0, stream>>>(ctxb, wdb, bd, out, S_LEN, HID,
                                              HID, 16);
}